// Round 1
// 96.564 us; speedup vs baseline: 1.1804x; 1.1804x over previous
//
#include <hip/hip_runtime.h>
#include <math.h>

// Problem constants
constexpr int BN  = 16;    // batch
constexpr int HH  = 224;
constexpr int WW  = 224;
constexpr int CI  = 8;     // input channels
constexpr int FF  = 256;   // filter feature dim
constexpr int NC  = 16;    // output channels
constexpr int NP  = 1152;  // CI*NC*3*3 dynamic params per sample
// patch index p = cin*9 + dy*3 + dx  (p < 72), w[b][p][c] = dyn[b][p*16+c]

__device__ __forceinline__ float elu_f(float x) {
    return x > 0.0f ? x : (__expf(x) - 1.0f);
}

// ---------------- kernel 1: h = elu(filter_inpt @ W1 + b1) -------------------
// grid 32 blocks (16 samples x 2 halves), 128 threads
__global__ __launch_bounds__(128) void k_h(const float* __restrict__ fi,
                                           const float* __restrict__ W1,
                                           const float* __restrict__ b1,
                                           float* __restrict__ h_out) {
    __shared__ float x[FF];
    int bid = blockIdx.x;
    int b = bid >> 1, half = bid & 1;
    int t = threadIdx.x;
    x[t]       = fi[b * FF + t];
    x[t + 128] = fi[b * FF + t + 128];
    __syncthreads();
    int col = half * 128 + t;
    float acc = b1[col];
#pragma unroll 8
    for (int k = 0; k < FF; ++k) acc = fmaf(x[k], W1[k * FF + col], acc);
    h_out[b * FF + col] = elu_f(acc);
}

// ------------- kernel 2: dyn = h@Wd + bd ; bias = h@Wb + bb + dfn ------------
// grid 160 blocks (16 samples x 10 jobs), 128 threads
__global__ __launch_bounds__(128) void k_dyn(const float* __restrict__ h_in,
                                             const float* __restrict__ Wd,
                                             const float* __restrict__ bd,
                                             const float* __restrict__ Wb,
                                             const float* __restrict__ bb,
                                             const float* __restrict__ dfn,
                                             float* __restrict__ w_out,
                                             float* __restrict__ bias_out) {
    __shared__ float hl[FF];
    int bid = blockIdx.x;
    int b = bid / 10, j = bid % 10;
    int t = threadIdx.x;
    hl[t]       = h_in[b * FF + t];
    hl[t + 128] = h_in[b * FF + t + 128];
    __syncthreads();
    if (j < 9) {
        int i = j * 128 + t;          // i < 1152
        float acc = bd[i];
#pragma unroll 8
        for (int k = 0; k < FF; ++k) acc = fmaf(hl[k], Wd[k * NP + i], acc);
        w_out[b * NP + i] = acc;
    } else if (t < NC) {
        float acc = bb[t] + dfn[t];
        for (int k = 0; k < FF; ++k) acc = fmaf(hl[k], Wb[k * NC + t], acc);
        bias_out[b * NC + t] = acc;
    }
}

// ---------------- kernel 3: dynamic 3x3 conv + bias + elu --------------------
// 4 pixels per thread along x. 64-thread blocks (1 wave), tile 32x8 pixels.
// grid (7, 28, 16). Weights staged in LDS, read as wave-uniform broadcast.
__global__ __launch_bounds__(64, 3) void k_conv(const float* __restrict__ in,
                                                const float* __restrict__ w_all,
                                                const float* __restrict__ bias_all,
                                                float* __restrict__ out) {
    __shared__ float4 lw[NP / 4];            // 1152 floats = 288 float4 = 4.6 KB

    const int b = blockIdx.z;
    const int t = threadIdx.x;               // 0..63

    // ---- stage per-sample weights into LDS (288 float4 by 64 threads) ----
    const float4* __restrict__ wsrc = (const float4*)(w_all + (size_t)b * NP);
    lw[t]        = wsrc[t];
    lw[t + 64]   = wsrc[t + 64];
    lw[t + 128]  = wsrc[t + 128];
    lw[t + 192]  = wsrc[t + 192];
    if (t < 32) lw[t + 256] = wsrc[t + 256];
    __syncthreads();

    const int tx = t & 7;                    // 0..7  -> x block of 4
    const int ty = t >> 3;                   // 0..7  -> row
    const int x0 = blockIdx.x * 32 + tx * 4;
    const int y  = blockIdx.y * 8 + ty;

    // ---- init accumulators with per-sample bias ----
    const float4* __restrict__ bb4 = (const float4*)(bias_all + b * NC);
    const float4 bv0 = bb4[0], bv1 = bb4[1], bv2 = bb4[2], bv3 = bb4[3];
    float acc[4][16];
#pragma unroll
    for (int p = 0; p < 4; ++p) {
        acc[p][0]  = bv0.x; acc[p][1]  = bv0.y; acc[p][2]  = bv0.z; acc[p][3]  = bv0.w;
        acc[p][4]  = bv1.x; acc[p][5]  = bv1.y; acc[p][6]  = bv1.z; acc[p][7]  = bv1.w;
        acc[p][8]  = bv2.x; acc[p][9]  = bv2.y; acc[p][10] = bv2.z; acc[p][11] = bv2.w;
        acc[p][12] = bv3.x; acc[p][13] = bv3.y; acc[p][14] = bv3.z; acc[p][15] = bv3.w;
    }

    // ---- column indices / validity, computed once ----
    int  cx[6];
    bool okc[6];
#pragma unroll
    for (int i = 0; i < 6; ++i) {
        const int c = x0 - 1 + i;
        okc[i] = (unsigned)c < (unsigned)WW;
        cx[i]  = min(max(c, 0), WW - 1);
    }

#pragma unroll 1
    for (int dy = 0; dy < 3; ++dy) {
        const int  vy  = y + dy - 1;
        const bool oky = (unsigned)vy < (unsigned)HH;
        const int  cy  = min(max(vy, 0), HH - 1);
        const float* __restrict__ rowp = in + (((size_t)b * HH + cy) * WW) * CI;

        // load 6 columns x 8 channels of this input row into registers
        float rv[48];
#pragma unroll
        for (int i = 0; i < 6; ++i) {
            const float4* cp = (const float4*)(rowp + (size_t)cx[i] * CI);
            float4 u0 = cp[0];
            float4 u1 = cp[1];
            const bool ok = oky && okc[i];
            rv[i * 8 + 0] = ok ? u0.x : 0.0f;
            rv[i * 8 + 1] = ok ? u0.y : 0.0f;
            rv[i * 8 + 2] = ok ? u0.z : 0.0f;
            rv[i * 8 + 3] = ok ? u0.w : 0.0f;
            rv[i * 8 + 4] = ok ? u1.x : 0.0f;
            rv[i * 8 + 5] = ok ? u1.y : 0.0f;
            rv[i * 8 + 6] = ok ? u1.z : 0.0f;
            rv[i * 8 + 7] = ok ? u1.w : 0.0f;
        }

        // taps for this dy: (cin, dx); weight float4 index = cin*36 + dy*12 + dx*4
        const float4* __restrict__ lwd = lw + dy * 12;
#pragma unroll
        for (int cin = 0; cin < 8; ++cin) {
#pragma unroll
            for (int dx = 0; dx < 3; ++dx) {
                const float4* wp = lwd + cin * 36 + dx * 4;
                const float4 w0 = wp[0], w1 = wp[1], w2 = wp[2], w3 = wp[3];
#pragma unroll
                for (int p = 0; p < 4; ++p) {
                    const float v = rv[(p + dx) * 8 + cin];
                    acc[p][0]  = fmaf(v, w0.x, acc[p][0]);
                    acc[p][1]  = fmaf(v, w0.y, acc[p][1]);
                    acc[p][2]  = fmaf(v, w0.z, acc[p][2]);
                    acc[p][3]  = fmaf(v, w0.w, acc[p][3]);
                    acc[p][4]  = fmaf(v, w1.x, acc[p][4]);
                    acc[p][5]  = fmaf(v, w1.y, acc[p][5]);
                    acc[p][6]  = fmaf(v, w1.z, acc[p][6]);
                    acc[p][7]  = fmaf(v, w1.w, acc[p][7]);
                    acc[p][8]  = fmaf(v, w2.x, acc[p][8]);
                    acc[p][9]  = fmaf(v, w2.y, acc[p][9]);
                    acc[p][10] = fmaf(v, w2.z, acc[p][10]);
                    acc[p][11] = fmaf(v, w2.w, acc[p][11]);
                    acc[p][12] = fmaf(v, w3.x, acc[p][12]);
                    acc[p][13] = fmaf(v, w3.y, acc[p][13]);
                    acc[p][14] = fmaf(v, w3.z, acc[p][14]);
                    acc[p][15] = fmaf(v, w3.w, acc[p][15]);
                }
            }
        }
    }

    // ---- epilogue: elu + store 4 pixels ----
    const size_t obase = ((size_t)b * HH + y) * WW + x0;
#pragma unroll
    for (int p = 0; p < 4; ++p) {
        float r[16];
#pragma unroll
        for (int c = 0; c < 16; ++c) r[c] = elu_f(acc[p][c]);
        float4* o4 = (float4*)(out + (obase + p) * NC);
        o4[0] = make_float4(r[0],  r[1],  r[2],  r[3]);
        o4[1] = make_float4(r[4],  r[5],  r[6],  r[7]);
        o4[2] = make_float4(r[8],  r[9],  r[10], r[11]);
        o4[3] = make_float4(r[12], r[13], r[14], r[15]);
    }
}

extern "C" void kernel_launch(void* const* d_in, const int* in_sizes, int n_in,
                              void* d_out, int out_size, void* d_ws, size_t ws_size,
                              hipStream_t stream) {
    const float* inpt = (const float*)d_in[0];
    const float* fi   = (const float*)d_in[1];
    const float* W1   = (const float*)d_in[2];
    const float* b1   = (const float*)d_in[3];
    const float* Wd   = (const float*)d_in[4];
    const float* bd   = (const float*)d_in[5];
    const float* Wb   = (const float*)d_in[6];
    const float* bb   = (const float*)d_in[7];
    const float* dfn  = (const float*)d_in[8];
    float* out = (float*)d_out;

    float* ws    = (float*)d_ws;
    float* h     = ws;                    // 16*256   = 4096 floats
    float* wDyn  = ws + 4096;             // 16*1152  = 18432 floats
    float* biasA = ws + 4096 + 18432;     // 16*16    = 256 floats

    k_h  <<<32, 128, 0, stream>>>(fi, W1, b1, h);
    k_dyn<<<160, 128, 0, stream>>>(h, Wd, bd, Wb, bb, dfn, wDyn, biasA);
    k_conv<<<dim3(7, 28, BN), 64, 0, stream>>>(inpt, wDyn, biasA, out);
}

// Round 2
// 83.332 us; speedup vs baseline: 1.3678x; 1.1588x over previous
//
#include <hip/hip_runtime.h>
#include <math.h>

// Problem constants
constexpr int BN  = 16;    // batch
constexpr int HH  = 224;
constexpr int WW  = 224;
constexpr int CI  = 8;     // input channels
constexpr int FF  = 256;   // filter feature dim
constexpr int NC  = 16;    // output channels
constexpr int NP  = 1152;  // CI*NC*3*3 dynamic params per sample
// patch index p = cin*9 + dy*3 + dx  (p < 72), w[b][p][c] = dyn[b][p*16+c]

__device__ __forceinline__ float elu_f(float x) {
    return x > 0.0f ? x : (__expf(x) - 1.0f);
}

// ---------------- kernel 1: h = elu(filter_inpt @ W1 + b1) -------------------
// grid 32 blocks (16 samples x 2 halves), 128 threads
__global__ __launch_bounds__(128) void k_h(const float* __restrict__ fi,
                                           const float* __restrict__ W1,
                                           const float* __restrict__ b1,
                                           float* __restrict__ h_out) {
    __shared__ float x[FF];
    int bid = blockIdx.x;
    int b = bid >> 1, half = bid & 1;
    int t = threadIdx.x;
    x[t]       = fi[b * FF + t];
    x[t + 128] = fi[b * FF + t + 128];
    __syncthreads();
    int col = half * 128 + t;
    float acc = b1[col];
#pragma unroll 8
    for (int k = 0; k < FF; ++k) acc = fmaf(x[k], W1[k * FF + col], acc);
    h_out[b * FF + col] = elu_f(acc);
}

// ------------- kernel 2: dyn = h@Wd + bd ; bias = h@Wb + bb + dfn ------------
// grid 160 blocks (16 samples x 10 jobs), 128 threads
__global__ __launch_bounds__(128) void k_dyn(const float* __restrict__ h_in,
                                             const float* __restrict__ Wd,
                                             const float* __restrict__ bd,
                                             const float* __restrict__ Wb,
                                             const float* __restrict__ bb,
                                             const float* __restrict__ dfn,
                                             float* __restrict__ w_out,
                                             float* __restrict__ bias_out) {
    __shared__ float hl[FF];
    int bid = blockIdx.x;
    int b = bid / 10, j = bid % 10;
    int t = threadIdx.x;
    hl[t]       = h_in[b * FF + t];
    hl[t + 128] = h_in[b * FF + t + 128];
    __syncthreads();
    if (j < 9) {
        int i = j * 128 + t;          // i < 1152
        float acc = bd[i];
#pragma unroll 8
        for (int k = 0; k < FF; ++k) acc = fmaf(hl[k], Wd[k * NP + i], acc);
        w_out[b * NP + i] = acc;
    } else if (t < NC) {
        float acc = bb[t] + dfn[t];
        for (int k = 0; k < FF; ++k) acc = fmaf(hl[k], Wb[k * NC + t], acc);
        bias_out[b * NC + t] = acc;
    }
}

// ---------------- kernel 3: dynamic 3x3 conv + bias + elu --------------------
// 2 pixels per thread along x. 256-thread blocks (4 waves), tile 32x16 pixels.
// grid (7, 14, 16). Weights staged in LDS, read as wave-uniform broadcast.
// Register budget: acc 32 + row 32 + tap 16 + misc ~= 95-110; cap 128 (4 w/SIMD).
__global__ __launch_bounds__(256, 4) void k_conv(const float* __restrict__ in,
                                                 const float* __restrict__ w_all,
                                                 const float* __restrict__ bias_all,
                                                 float* __restrict__ out) {
    __shared__ float4 lw[NP / 4];            // 288 float4 = 4.6 KB

    const int b = blockIdx.z;
    const int t = threadIdx.x;               // 0..255

    // ---- stage per-sample weights into LDS ----
    const float4* __restrict__ wsrc = (const float4*)(w_all + (size_t)b * NP);
    if (t < 256) lw[t] = wsrc[t];
    if (t < 32)  lw[t + 256] = wsrc[t + 256];
    __syncthreads();

    const int tx = t & 15;                   // 0..15 -> x block of 2
    const int ty = t >> 4;                   // 0..15 -> row
    const int x0 = blockIdx.x * 32 + tx * 2;
    const int y  = blockIdx.y * 16 + ty;

    // ---- init accumulators with per-sample bias ----
    const float4* __restrict__ bb4 = (const float4*)(bias_all + b * NC);
    const float4 bv0 = bb4[0], bv1 = bb4[1], bv2 = bb4[2], bv3 = bb4[3];
    float acc[2][16];
#pragma unroll
    for (int p = 0; p < 2; ++p) {
        acc[p][0]  = bv0.x; acc[p][1]  = bv0.y; acc[p][2]  = bv0.z; acc[p][3]  = bv0.w;
        acc[p][4]  = bv1.x; acc[p][5]  = bv1.y; acc[p][6]  = bv1.z; acc[p][7]  = bv1.w;
        acc[p][8]  = bv2.x; acc[p][9]  = bv2.y; acc[p][10] = bv2.z; acc[p][11] = bv2.w;
        acc[p][12] = bv3.x; acc[p][13] = bv3.y; acc[p][14] = bv3.z; acc[p][15] = bv3.w;
    }

    // ---- column indices / validity (cols x0-1 .. x0+2), computed once ----
    int  cx[4];
    bool okc[4];
#pragma unroll
    for (int i = 0; i < 4; ++i) {
        const int c = x0 - 1 + i;
        okc[i] = (unsigned)c < (unsigned)WW;
        cx[i]  = min(max(c, 0), WW - 1);
    }

#pragma unroll 1
    for (int dy = 0; dy < 3; ++dy) {
        const int  vy  = y + dy - 1;
        const bool oky = (unsigned)vy < (unsigned)HH;
        const int  cy  = min(max(vy, 0), HH - 1);
        const float* __restrict__ rowp = in + (((size_t)b * HH + cy) * WW) * CI;

        // load 4 columns x 8 channels of this input row into registers
        float rv[32];
#pragma unroll
        for (int i = 0; i < 4; ++i) {
            const float4* cp = (const float4*)(rowp + (size_t)cx[i] * CI);
            float4 u0 = cp[0];
            float4 u1 = cp[1];
            const bool ok = oky && okc[i];
            rv[i * 8 + 0] = ok ? u0.x : 0.0f;
            rv[i * 8 + 1] = ok ? u0.y : 0.0f;
            rv[i * 8 + 2] = ok ? u0.z : 0.0f;
            rv[i * 8 + 3] = ok ? u0.w : 0.0f;
            rv[i * 8 + 4] = ok ? u1.x : 0.0f;
            rv[i * 8 + 5] = ok ? u1.y : 0.0f;
            rv[i * 8 + 6] = ok ? u1.z : 0.0f;
            rv[i * 8 + 7] = ok ? u1.w : 0.0f;
        }

        // taps for this dy: weight float4 index = cin*36 + dy*12 + dx*4
        const float4* __restrict__ lwd = lw + dy * 12;
#pragma unroll
        for (int cin = 0; cin < 8; ++cin) {
#pragma unroll
            for (int dx = 0; dx < 3; ++dx) {
                const float4* wp = lwd + cin * 36 + dx * 4;
                const float4 w0 = wp[0], w1 = wp[1], w2 = wp[2], w3 = wp[3];
#pragma unroll
                for (int p = 0; p < 2; ++p) {
                    const float v = rv[(p + dx) * 8 + cin];
                    acc[p][0]  = fmaf(v, w0.x, acc[p][0]);
                    acc[p][1]  = fmaf(v, w0.y, acc[p][1]);
                    acc[p][2]  = fmaf(v, w0.z, acc[p][2]);
                    acc[p][3]  = fmaf(v, w0.w, acc[p][3]);
                    acc[p][4]  = fmaf(v, w1.x, acc[p][4]);
                    acc[p][5]  = fmaf(v, w1.y, acc[p][5]);
                    acc[p][6]  = fmaf(v, w1.z, acc[p][6]);
                    acc[p][7]  = fmaf(v, w1.w, acc[p][7]);
                    acc[p][8]  = fmaf(v, w2.x, acc[p][8]);
                    acc[p][9]  = fmaf(v, w2.y, acc[p][9]);
                    acc[p][10] = fmaf(v, w2.z, acc[p][10]);
                    acc[p][11] = fmaf(v, w2.w, acc[p][11]);
                    acc[p][12] = fmaf(v, w3.x, acc[p][12]);
                    acc[p][13] = fmaf(v, w3.y, acc[p][13]);
                    acc[p][14] = fmaf(v, w3.z, acc[p][14]);
                    acc[p][15] = fmaf(v, w3.w, acc[p][15]);
                }
            }
        }
    }

    // ---- epilogue: elu + store 2 pixels ----
    const size_t obase = ((size_t)b * HH + y) * WW + x0;
#pragma unroll
    for (int p = 0; p < 2; ++p) {
        float r[16];
#pragma unroll
        for (int c = 0; c < 16; ++c) r[c] = elu_f(acc[p][c]);
        float4* o4 = (float4*)(out + (obase + p) * NC);
        o4[0] = make_float4(r[0],  r[1],  r[2],  r[3]);
        o4[1] = make_float4(r[4],  r[5],  r[6],  r[7]);
        o4[2] = make_float4(r[8],  r[9],  r[10], r[11]);
        o4[3] = make_float4(r[12], r[13], r[14], r[15]);
    }
}

extern "C" void kernel_launch(void* const* d_in, const int* in_sizes, int n_in,
                              void* d_out, int out_size, void* d_ws, size_t ws_size,
                              hipStream_t stream) {
    const float* inpt = (const float*)d_in[0];
    const float* fi   = (const float*)d_in[1];
    const float* W1   = (const float*)d_in[2];
    const float* b1   = (const float*)d_in[3];
    const float* Wd   = (const float*)d_in[4];
    const float* bd   = (const float*)d_in[5];
    const float* Wb   = (const float*)d_in[6];
    const float* bb   = (const float*)d_in[7];
    const float* dfn  = (const float*)d_in[8];
    float* out = (float*)d_out;

    float* ws    = (float*)d_ws;
    float* h     = ws;                    // 16*256   = 4096 floats
    float* wDyn  = ws + 4096;             // 16*1152  = 18432 floats
    float* biasA = ws + 4096 + 18432;     // 16*16    = 256 floats

    k_h  <<<32, 128, 0, stream>>>(fi, W1, b1, h);
    k_dyn<<<160, 128, 0, stream>>>(h, Wd, bd, Wb, bb, dfn, wDyn, biasA);
    k_conv<<<dim3(7, 14, BN), 256, 0, stream>>>(inpt, wDyn, biasA, out);
}